// Round 1
// baseline (289.680 us; speedup 1.0000x reference)
//
#include <hip/hip_runtime.h>

// VQ-VAE vector quantizer forward for MI355X (gfx950).
// latents: [B=32, D=64, H=64, W=64] fp32; emb: [K=512, D=64] fp32.
// out[0..QOUT-1] = quantized latents in [B, D, H, W] layout (q_st == q in value)
// out[QOUT]     = vq_loss = 1.25 * mean((q - lat)^2)

namespace {
constexpr int K      = 512;
constexpr int D      = 64;
constexpr int HW     = 4096;           // H*W
constexpr int NPIX   = 32 * HW;        // 131072 pixels
constexpr int QOUT   = NPIX * D;       // 8388608 output elements
constexpr int CHUNK  = 128;            // codes per LDS chunk (32 KB)
constexpr int THREADS = 256;
}

// Precompute 0.5*||e_k||^2 into ws; also zero the loss accumulator.
__global__ void vq_norms_kernel(const float* __restrict__ emb,
                                float* __restrict__ norm_half,
                                float* __restrict__ loss) {
    int k = blockIdx.x * blockDim.x + threadIdx.x;
    if (k == 0) *loss = 0.0f;
    if (k < K) {
        const float4* row = (const float4*)(emb + k * D);
        float s = 0.0f;
#pragma unroll
        for (int i = 0; i < D / 4; ++i) {
            float4 v = row[i];
            s += v.x * v.x; s += v.y * v.y; s += v.z * v.z; s += v.w * v.w;
        }
        norm_half[k] = 0.5f * s;
    }
}

__global__ __launch_bounds__(THREADS) void vq_main_kernel(
    const float* __restrict__ lat,
    const float* __restrict__ emb,
    const float* __restrict__ norm_half,
    float* __restrict__ out,
    float* __restrict__ loss) {
    __shared__ float se[CHUNK * D];   // code chunk, [k][d] row-major, 32 KB
    __shared__ float sn[CHUNK];       // 0.5*||e||^2 for the chunk

    const int tid = threadIdx.x;
    const int n   = blockIdx.x * THREADS + tid;   // pixel id = b*4096 + hw
    const int b   = n >> 12;                      // / 4096
    const int hw  = n & (HW - 1);
    const float* latp = lat + (size_t)(b * D) * HW + hw;

    // x vector for this pixel in VGPRs; coalesced loads (lane <-> hw).
    float x[D];
#pragma unroll
    for (int d = 0; d < D; ++d) x[d] = latp[d * HW];

    float best  = 3.4e38f;
    int   bestk = 0;

    for (int k0 = 0; k0 < K; k0 += CHUNK) {
        __syncthreads();
        {
            // stage CHUNK*D floats, coalesced float4 copies
            const float4* src = (const float4*)(emb + k0 * D);
            float4* dst = (float4*)se;
#pragma unroll
            for (int i = 0; i < (CHUNK * D / 4) / THREADS; ++i)
                dst[i * THREADS + tid] = src[i * THREADS + tid];
            if (tid < CHUNK) sn[tid] = norm_half[k0 + tid];
        }
        __syncthreads();

        // 4 codes at a time: 4 independent FMA chains; LDS reads are
        // wave-uniform addresses -> broadcast, conflict-free.
#pragma unroll 1
        for (int kk = 0; kk < CHUNK; kk += 4) {
            const float* e0 = se + (kk + 0) * D;
            const float* e1 = se + (kk + 1) * D;
            const float* e2 = se + (kk + 2) * D;
            const float* e3 = se + (kk + 3) * D;
            float a0 = 0.0f, a1 = 0.0f, a2 = 0.0f, a3 = 0.0f;
#pragma unroll
            for (int d = 0; d < D; d += 4) {
                float4 v0 = *(const float4*)(e0 + d);
                float4 v1 = *(const float4*)(e1 + d);
                float4 v2 = *(const float4*)(e2 + d);
                float4 v3 = *(const float4*)(e3 + d);
                a0 += x[d + 0] * v0.x; a0 += x[d + 1] * v0.y;
                a0 += x[d + 2] * v0.z; a0 += x[d + 3] * v0.w;
                a1 += x[d + 0] * v1.x; a1 += x[d + 1] * v1.y;
                a1 += x[d + 2] * v1.z; a1 += x[d + 3] * v1.w;
                a2 += x[d + 0] * v2.x; a2 += x[d + 1] * v2.y;
                a2 += x[d + 2] * v2.z; a2 += x[d + 3] * v2.w;
                a3 += x[d + 0] * v3.x; a3 += x[d + 1] * v3.y;
                a3 += x[d + 2] * v3.z; a3 += x[d + 3] * v3.w;
            }
            // score = 0.5||e||^2 - x.e  (== (dist - ||x||^2)/2, same argmin)
            float s0 = sn[kk + 0] - a0;
            float s1 = sn[kk + 1] - a1;
            float s2 = sn[kk + 2] - a2;
            float s3 = sn[kk + 3] - a3;
            if (s0 < best) { best = s0; bestk = k0 + kk + 0; }
            if (s1 < best) { best = s1; bestk = k0 + kk + 1; }
            if (s2 < best) { best = s2; bestk = k0 + kk + 2; }
            if (s3 < best) { best = s3; bestk = k0 + kk + 3; }
        }
    }

    // Epilogue: gather winning code (L2-resident table), write transposed
    // output (coalesced per-d), accumulate squared error.
    const float* eb   = emb + bestk * D;
    float* outp       = out + (size_t)(b * D) * HW + hw;
    float  sq = 0.0f;
#pragma unroll
    for (int i = 0; i < D / 4; ++i) {
        float4 v = *(const float4*)(eb + 4 * i);
        float d0 = v.x - x[4 * i + 0];
        float d1 = v.y - x[4 * i + 1];
        float d2 = v.z - x[4 * i + 2];
        float d3 = v.w - x[4 * i + 3];
        sq += d0 * d0; sq += d1 * d1; sq += d2 * d2; sq += d3 * d3;
        outp[(4 * i + 0) * HW] = v.x;
        outp[(4 * i + 1) * HW] = v.y;
        outp[(4 * i + 2) * HW] = v.z;
        outp[(4 * i + 3) * HW] = v.w;
    }

    // wave(64)-level reduction, then one atomic per wave.
#pragma unroll
    for (int off = 32; off > 0; off >>= 1)
        sq += __shfl_down(sq, off, 64);
    if ((tid & 63) == 0)
        atomicAdd(loss, sq * (1.25f / (float)QOUT));
}

extern "C" void kernel_launch(void* const* d_in, const int* in_sizes, int n_in,
                              void* d_out, int out_size, void* d_ws, size_t ws_size,
                              hipStream_t stream) {
    const float* lat = (const float*)d_in[0];
    const float* emb = (const float*)d_in[1];
    float* out       = (float*)d_out;
    float* loss      = out + QOUT;          // scalar vq_loss slot
    float* norm_half = (float*)d_ws;        // 512 floats of scratch

    vq_norms_kernel<<<(K + 255) / 256, 256, 0, stream>>>(emb, norm_half, loss);
    vq_main_kernel<<<NPIX / THREADS, THREADS, 0, stream>>>(lat, emb, norm_half,
                                                           out, loss);
}

// Round 2
// 116.473 us; speedup vs baseline: 2.4871x; 2.4871x over previous
//
#include <hip/hip_runtime.h>

// VQ-VAE quantizer via MFMA on MI355X (gfx950).
// score(k) = x.e_k - 0.5||e_k||^2, argmax over K=512 codes per pixel.
// Augmented GEMM: A = ext codes [512 x 80] bf16 (dim 64 = -0.5||e||^2),
//                 B = [x, 1, 0...] per pixel -> mfma_f32_32x32x16_bf16.

typedef __bf16 bf16_t;
typedef __attribute__((ext_vector_type(8))) __bf16 bf16x8;
typedef __attribute__((ext_vector_type(16))) float floatx16;

namespace {
constexpr int K    = 512;
constexpr int D    = 64;
constexpr int HW   = 4096;
constexpr int NPIX = 32 * HW;       // 131072
constexpr int QOUT = NPIX * D;      // 8388608
constexpr int DEXT = 80;            // 64 dims + score-bias dim + pad (5 k-steps of 16)
}

// Build augmented bf16 code table in ws; zero the loss slot.
__global__ void vq_prep(const float* __restrict__ emb,
                        bf16_t* __restrict__ ext,
                        float* __restrict__ loss) {
    int k = blockIdx.x * blockDim.x + threadIdx.x;
    if (k == 0) *loss = 0.0f;
    if (k < K) {
        float s = 0.0f;
        bf16_t row[DEXT];
#pragma unroll
        for (int d = 0; d < D; ++d) {
            float v = emb[k * D + d];
            s += v * v;
            row[d] = (bf16_t)v;
        }
        row[64] = (bf16_t)(-0.5f * s);
#pragma unroll
        for (int d = 65; d < DEXT; ++d) row[d] = (bf16_t)0.0f;
#pragma unroll
        for (int d = 0; d < DEXT; ++d) ext[k * DEXT + d] = row[d];
    }
}

__global__ __launch_bounds__(256) void vq_mfma(
    const float* __restrict__ lat,
    const float* __restrict__ emb,
    const bf16_t* __restrict__ ext,
    float* __restrict__ out,
    float* __restrict__ loss) {
    const int lane = threadIdx.x & 63;
    const int wave = threadIdx.x >> 6;
    const int col  = lane & 31;       // pixel within tile (B n) AND code row (A m)
    const int half = lane >> 5;       // k-group selector
    const int n    = blockIdx.x * 128 + wave * 32 + col;   // pixel id
    const int b    = n >> 12;
    const int hw   = n & (HW - 1);
    const float* latp = lat + (size_t)b * D * HW + hw;

    // Load this pixel's 32 dims (this lane's k-pattern), keep fp32 for loss,
    // build bf16 B fragments. d = s*16 + half*8 + j.
    float  xf[32];
    bf16x8 bfrag[5];
#pragma unroll
    for (int s = 0; s < 4; ++s) {
#pragma unroll
        for (int j = 0; j < 8; ++j) {
            int d = s * 16 + half * 8 + j;
            float v = latp[(size_t)d * HW];
            xf[s * 8 + j] = v;
            bfrag[s][j] = (bf16_t)v;
        }
    }
#pragma unroll
    for (int j = 0; j < 8; ++j) bfrag[4][j] = (bf16_t)0.0f;
    if (half == 0) bfrag[4][0] = (bf16_t)1.0f;   // augmented dim 64 = 1

    float best  = -3.4e38f;
    int   bestk = 0;
    for (int t = 0; t < 16; ++t) {
        floatx16 acc;
#pragma unroll
        for (int r = 0; r < 16; ++r) acc[r] = 0.0f;
        const bf16_t* arow = ext + ((size_t)(t * 32 + col)) * DEXT + half * 8;
#pragma unroll
        for (int s = 0; s < 5; ++s) {
            bf16x8 afrag = *(const bf16x8*)(arow + s * 16);
            acc = __builtin_amdgcn_mfma_f32_32x32x16_bf16(afrag, bfrag[s], acc,
                                                          0, 0, 0);
        }
#pragma unroll
        for (int r = 0; r < 16; ++r) {
            if (acc[r] > best) {
                best  = acc[r];
                bestk = t * 32 + (r & 3) + 8 * (r >> 2) + 4 * half;
            }
        }
    }

    // Merge the two half-wave row sets (same pixel col).
    {
        float ob  = __shfl_xor(best, 32, 64);
        int   obk = __shfl_xor(bestk, 32, 64);
        if (ob > best || (ob == best && obk < bestk)) { best = ob; bestk = obk; }
    }

    // Epilogue: gather winning code (fp32), write transposed output, loss.
    const float* eb   = emb + bestk * D + half * 8;
    float* outp       = out + (size_t)b * D * HW + hw;
    float  sq = 0.0f;
#pragma unroll
    for (int s = 0; s < 4; ++s) {
        float4 q0 = *(const float4*)(eb + s * 16);
        float4 q1 = *(const float4*)(eb + s * 16 + 4);
        float d0 = q0.x - xf[s * 8 + 0], d1 = q0.y - xf[s * 8 + 1];
        float d2 = q0.z - xf[s * 8 + 2], d3 = q0.w - xf[s * 8 + 3];
        float d4 = q1.x - xf[s * 8 + 4], d5 = q1.y - xf[s * 8 + 5];
        float d6 = q1.z - xf[s * 8 + 6], d7 = q1.w - xf[s * 8 + 7];
        sq += d0 * d0 + d1 * d1 + d2 * d2 + d3 * d3;
        sq += d4 * d4 + d5 * d5 + d6 * d6 + d7 * d7;
        const int dbase = s * 16 + half * 8;
        outp[(size_t)(dbase + 0) * HW] = q0.x;
        outp[(size_t)(dbase + 1) * HW] = q0.y;
        outp[(size_t)(dbase + 2) * HW] = q0.z;
        outp[(size_t)(dbase + 3) * HW] = q0.w;
        outp[(size_t)(dbase + 4) * HW] = q1.x;
        outp[(size_t)(dbase + 5) * HW] = q1.y;
        outp[(size_t)(dbase + 6) * HW] = q1.z;
        outp[(size_t)(dbase + 7) * HW] = q1.w;
    }

    // wave reduce, block reduce, one atomic per block.
#pragma unroll
    for (int off = 32; off > 0; off >>= 1) sq += __shfl_down(sq, off, 64);
    __shared__ float part[4];
    if (lane == 0) part[wave] = sq;
    __syncthreads();
    if (threadIdx.x == 0) {
        float t = part[0] + part[1] + part[2] + part[3];
        atomicAdd(loss, t * (1.25f / (float)QOUT));
    }
}

extern "C" void kernel_launch(void* const* d_in, const int* in_sizes, int n_in,
                              void* d_out, int out_size, void* d_ws, size_t ws_size,
                              hipStream_t stream) {
    const float* lat = (const float*)d_in[0];
    const float* emb = (const float*)d_in[1];
    float* out       = (float*)d_out;
    float* loss      = out + QOUT;
    bf16_t* ext      = (bf16_t*)d_ws;   // 512*80*2 = 80 KB scratch

    vq_prep<<<2, 256, 0, stream>>>(emb, ext, loss);
    vq_mfma<<<NPIX / 128, 256, 0, stream>>>(lat, emb, ext, out, loss);
}

// Round 4
// 108.064 us; speedup vs baseline: 2.6806x; 1.0778x over previous
//
#include <hip/hip_runtime.h>

// VQ-VAE quantizer via MFMA on MI355X (gfx950).
// score(k) = x.e_k - 0.5||e_k||^2, argmax over K=512 codes per pixel.
// Augmented GEMM: A = ext codes [512 x 80] bf16 (dim 64 = -0.5||e||^2),
//                 B = [x, 1, 0...] per pixel -> mfma_f32_32x32x16_bf16.
// R3: fix R2's wave-stride bug (waves cover 64 px but strode 128 -> half the
//     pixels were never computed; loss came out at exactly half).
//     wave base = blockIdx*256 + wave*64, grid = NPIX/256.

typedef __bf16 bf16_t;
typedef __attribute__((ext_vector_type(8))) __bf16 bf16x8;
typedef __attribute__((ext_vector_type(16))) float floatx16;

namespace {
constexpr int K    = 512;
constexpr int D    = 64;
constexpr int HW   = 4096;
constexpr int NPIX = 32 * HW;       // 131072
constexpr int QOUT = NPIX * D;      // 8388608
constexpr int DEXT = 80;            // 64 dims + score-bias dim + pad (5 k-steps)
constexpr int G    = 2;             // pixel groups per wave (64 px/wave)
}

// Build augmented bf16 code table in ws; zero the loss slot.
__global__ __launch_bounds__(64) void vq_prep(const float* __restrict__ emb,
                                              bf16_t* __restrict__ ext,
                                              float* __restrict__ loss) {
    int k = blockIdx.x * 64 + threadIdx.x;
    if (k == 0) *loss = 0.0f;
    if (k >= K) return;
    const float4* row = (const float4*)(emb + k * D);
    float4 v[16];
#pragma unroll
    for (int i = 0; i < 16; ++i) v[i] = row[i];
    float s = 0.0f;
#pragma unroll
    for (int i = 0; i < 16; ++i)
        s += v[i].x * v[i].x + v[i].y * v[i].y + v[i].z * v[i].z + v[i].w * v[i].w;
    bf16_t r[DEXT];
#pragma unroll
    for (int i = 0; i < 16; ++i) {
        r[4 * i + 0] = (bf16_t)v[i].x;
        r[4 * i + 1] = (bf16_t)v[i].y;
        r[4 * i + 2] = (bf16_t)v[i].z;
        r[4 * i + 3] = (bf16_t)v[i].w;
    }
    r[64] = (bf16_t)(-0.5f * s);
#pragma unroll
    for (int i = 65; i < DEXT; ++i) r[i] = (bf16_t)0.0f;
#pragma unroll
    for (int i = 0; i < DEXT / 8; ++i)
        ((bf16x8*)(ext + k * DEXT))[i] = *(const bf16x8*)(r + 8 * i);
}

__global__ __launch_bounds__(256) void vq_mfma(
    const float* __restrict__ lat,
    const float* __restrict__ emb,
    const bf16_t* __restrict__ ext,
    float* __restrict__ out,
    float* __restrict__ loss) {
    const int lane = threadIdx.x & 63;
    const int wave = threadIdx.x >> 6;
    const int col  = lane & 31;       // pixel within group (B n) AND code row (A m)
    const int half = lane >> 5;       // k-group selector
    const int nb   = blockIdx.x * (64 * G * 4) / 2 + wave * 64;  // 256/block, 64/wave

    // Per-group pixel ids and B fragments (x in bf16; d = s*16 + half*8 + j).
    int bg[G], hwg[G];
    bf16x8 bfrag[G][5];
#pragma unroll
    for (int g = 0; g < G; ++g) {
        int n = nb + g * 32 + col;
        bg[g] = n >> 12;
        hwg[g] = n & (HW - 1);
        const float* latp = lat + (size_t)bg[g] * D * HW + hwg[g];
#pragma unroll
        for (int s = 0; s < 4; ++s) {
#pragma unroll
            for (int j = 0; j < 8; ++j) {
                int d = s * 16 + half * 8 + j;
                bfrag[g][s][j] = (bf16_t)latp[(size_t)d * HW];
            }
        }
#pragma unroll
        for (int j = 0; j < 8; ++j) bfrag[g][4][j] = (bf16_t)0.0f;
        if (half == 0) bfrag[g][4][0] = (bf16_t)1.0f;   // augmented dim 64 = 1
    }

    float best[G];
    int   bestk[G];
#pragma unroll
    for (int g = 0; g < G; ++g) { best[g] = -3.4e38f; bestk[g] = 0; }

#pragma unroll 4
    for (int t = 0; t < 16; ++t) {
        const bf16_t* arow = ext + ((size_t)(t * 32 + col)) * DEXT + half * 8;
        bf16x8 af[5];
#pragma unroll
        for (int s = 0; s < 5; ++s) af[s] = *(const bf16x8*)(arow + s * 16);

        floatx16 acc[G];
#pragma unroll
        for (int g = 0; g < G; ++g) {
#pragma unroll
            for (int r = 0; r < 16; ++r) acc[g][r] = 0.0f;
#pragma unroll
            for (int s = 0; s < 5; ++s)
                acc[g] = __builtin_amdgcn_mfma_f32_32x32x16_bf16(
                    af[s], bfrag[g][s], acc[g], 0, 0, 0);
        }
#pragma unroll
        for (int g = 0; g < G; ++g) {
#pragma unroll
            for (int r = 0; r < 16; ++r) {
                if (acc[g][r] > best[g]) {
                    best[g]  = acc[g][r];
                    bestk[g] = t * 32 + (r & 3) + 8 * (r >> 2) + 4 * half;
                }
            }
        }
    }

    float sqtot = 0.0f;
#pragma unroll
    for (int g = 0; g < G; ++g) {
        // Merge the two half-wave row sets (same pixel col).
        float ob  = __shfl_xor(best[g], 32, 64);
        int   obk = __shfl_xor(bestk[g], 32, 64);
        if (ob > best[g] || (ob == best[g] && obk < bestk[g])) {
            best[g] = ob; bestk[g] = obk;
        }

        // Gather winning code (fp32), write transposed output, loss.
        const float* eb = emb + bestk[g] * D + half * 8;
        float* outp     = out + (size_t)bg[g] * D * HW + hwg[g];
        float sq = 0.0f;
#pragma unroll
        for (int s = 0; s < 4; ++s) {
            float4 q0 = *(const float4*)(eb + s * 16);
            float4 q1 = *(const float4*)(eb + s * 16 + 4);
            float x0 = (float)bfrag[g][s][0], x1 = (float)bfrag[g][s][1];
            float x2 = (float)bfrag[g][s][2], x3 = (float)bfrag[g][s][3];
            float x4 = (float)bfrag[g][s][4], x5 = (float)bfrag[g][s][5];
            float x6 = (float)bfrag[g][s][6], x7 = (float)bfrag[g][s][7];
            float d0 = q0.x - x0, d1 = q0.y - x1, d2 = q0.z - x2, d3 = q0.w - x3;
            float d4 = q1.x - x4, d5 = q1.y - x5, d6 = q1.z - x6, d7 = q1.w - x7;
            sq += d0 * d0 + d1 * d1 + d2 * d2 + d3 * d3;
            sq += d4 * d4 + d5 * d5 + d6 * d6 + d7 * d7;
            const int dbase = s * 16 + half * 8;
            outp[(size_t)(dbase + 0) * HW] = q0.x;
            outp[(size_t)(dbase + 1) * HW] = q0.y;
            outp[(size_t)(dbase + 2) * HW] = q0.z;
            outp[(size_t)(dbase + 3) * HW] = q0.w;
            outp[(size_t)(dbase + 4) * HW] = q1.x;
            outp[(size_t)(dbase + 5) * HW] = q1.y;
            outp[(size_t)(dbase + 6) * HW] = q1.z;
            outp[(size_t)(dbase + 7) * HW] = q1.w;
        }
        sqtot += sq;
    }

    // wave reduce, block reduce, one atomic per block.
#pragma unroll
    for (int off = 32; off > 0; off >>= 1) sqtot += __shfl_down(sqtot, off, 64);
    __shared__ float part[4];
    if (lane == 0) part[wave] = sqtot;
    __syncthreads();
    if (threadIdx.x == 0) {
        float t = part[0] + part[1] + part[2] + part[3];
        atomicAdd(loss, t * (1.25f / (float)QOUT));
    }
}

extern "C" void kernel_launch(void* const* d_in, const int* in_sizes, int n_in,
                              void* d_out, int out_size, void* d_ws, size_t ws_size,
                              hipStream_t stream) {
    const float* lat = (const float*)d_in[0];
    const float* emb = (const float*)d_in[1];
    float* out       = (float*)d_out;
    float* loss      = out + QOUT;
    bf16_t* ext      = (bf16_t*)d_ws;   // 512*80*2 = 80 KB scratch

    vq_prep<<<K / 64, 64, 0, stream>>>(emb, ext, loss);
    // 64 px/wave (G groups of 32), 4 waves/block -> 256 px/block.
    vq_mfma<<<NPIX / 256, 256, 0, stream>>>(lat, emb, ext, out, loss);
}